// Round 3
// baseline (868.360 us; speedup 1.0000x reference)
//
#include <hip/hip_runtime.h>
#include <hip/hip_cooperative_groups.h>
#include <math.h>

namespace cg = cooperative_groups;

#define SEQ  1024
#define DIM  64
#define MUV  (1.0f/1024.0f)

typedef __attribute__((ext_vector_type(8))) short bf16x8;
typedef __attribute__((ext_vector_type(4))) float f32x4;

__device__ __forceinline__ float frcp(float x){ return __builtin_amdgcn_rcpf(x); }
__device__ __forceinline__ float bf2f(unsigned short u){
  union { unsigned int i; float f; } v; v.i = ((unsigned int)u) << 16; return v.f;
}
__device__ __forceinline__ unsigned short f2bf(float f){
  union { float f; unsigned int i; } v; v.f = f;
  return (unsigned short)((v.i + 0x7FFFu + ((v.i >> 16) & 1u)) >> 16);
}

// One persistent block per CU: block = (head h, 64-row chunk r0).
// Kexp (64x1024 bf16) lives in LDS for the whole kernel.
__global__ __launch_bounds__(256, 1)
void sinkhorn_fused(const float* __restrict__ Q, const float* __restrict__ Kin,
                    const float* __restrict__ V, float* __restrict__ out)
{
  __shared__ unsigned short Kx[64 * 1024];  // 128KB bf16, row stride 2048B, XOR-swizzled
  __shared__ unsigned short QS[64 * 64];    // 8KB bf16 Q stage, row stride 128B, swizzled
  __shared__ unsigned short ST[64 * 64];    // 8KB bf16 stage (Kin chunks, later V chunks)
  __shared__ float bvec[1024];
  __shared__ float avec[64];

  const int bid  = blockIdx.x;
  const int h    = bid >> 4;
  const int r0   = (bid & 15) * 64;
  const int t    = threadIdx.x;
  const int lane = t & 63;
  const int w    = t >> 6;       // wave 0..3
  const int fr   = lane & 15;    // fragment row/col index
  const int fq   = lane >> 4;    // fragment k-group

  float* Pmat  = out + (size_t)16 * SEQ * DIM;  // p_attn region (16M floats)
  float* cpart = Pmat;                          // first 1MB reused as column partials

  const float* Qg = Q   + ((size_t)h * SEQ + r0) * DIM;
  const float* Kg = Kin + (size_t)h * SEQ * DIM;
  const float* Vg = V   + (size_t)h * SEQ * DIM;

  // ---------------- Phase 1: Kx = exp(-exp(Q K^T)/8) via bf16 MFMA ----------------
  {
    const int r = t >> 4, c4 = (t & 15) * 4;
#pragma unroll
    for (int q = 0; q < 4; q++){
      const int row = r + 16 * q;
      const float4 v = *(const float4*)(Qg + row * DIM + c4);
      ushort4 u4 = make_ushort4(f2bf(v.x), f2bf(v.y), f2bf(v.z), f2bf(v.w));
      *(ushort4*)((char*)QS + row * 128 + ((c4 * 2) ^ ((row & 7) << 4))) = u4;
    }
  }
  __syncthreads();

  const int qrow = w * 16 + fr;
  const bf16x8 qa0 = *(const bf16x8*)((char*)QS + qrow * 128 + ((fq * 16)      ^ ((qrow & 7) << 4)));
  const bf16x8 qa1 = *(const bf16x8*)((char*)QS + qrow * 128 + ((64 + fq * 16) ^ ((qrow & 7) << 4)));

  for (int cc = 0; cc < 16; cc++){
    __syncthreads();   // protect ST from previous chunk's readers
    {
      const int r = t >> 4, c4 = (t & 15) * 4;
      const float* g = Kg + (size_t)cc * 64 * DIM;
#pragma unroll
      for (int q = 0; q < 4; q++){
        const int row = r + 16 * q;
        const float4 v = *(const float4*)(g + row * DIM + c4);
        ushort4 u4 = make_ushort4(f2bf(v.x), f2bf(v.y), f2bf(v.z), f2bf(v.w));
        *(ushort4*)((char*)ST + row * 128 + ((c4 * 2) ^ ((row & 7) << 4))) = u4;
      }
    }
    __syncthreads();
#pragma unroll
    for (int ct = 0; ct < 4; ct++){
      const int krow = ct * 16 + fr;
      const bf16x8 kb0 = *(const bf16x8*)((char*)ST + krow * 128 + ((fq * 16)      ^ ((krow & 7) << 4)));
      const bf16x8 kb1 = *(const bf16x8*)((char*)ST + krow * 128 + ((64 + fq * 16) ^ ((krow & 7) << 4)));
      f32x4 acc = {0.f, 0.f, 0.f, 0.f};
      acc = __builtin_amdgcn_mfma_f32_16x16x32_bf16(qa0, kb0, acc, 0, 0, 0);
      acc = __builtin_amdgcn_mfma_f32_16x16x32_bf16(qa1, kb1, acc, 0, 0, 0);
      const int col = cc * 64 + ct * 16 + fr;
#pragma unroll
      for (int r = 0; r < 4; r++){
        const int row = w * 16 + fq * 4 + r;     // C layout: col=lane&15, row=(lane>>4)*4+r
        const float kv = __expf(-__expf(acc[r]) * 0.125f);
        *(unsigned short*)((char*)Kx + row * 2048 + ((col * 2) ^ ((row & 7) << 4))) = f2bf(kv);
      }
    }
  }
  __syncthreads();

  // ---------------- Phase 2: 10 Sinkhorn iterations, Kx resident in LDS ----------------
  cg::grid_group grid = cg::this_grid();

  for (int it = 0; it < 10; it++){
    if (it == 0){
#pragma unroll
      for (int q = 0; q < 4; q++) bvec[t * 4 + q] = 1.0f;     // b_0 = 1 (v=0)
    } else {
      float4 s = make_float4(0, 0, 0, 0);
      const float* cp = cpart + (size_t)h * 16 * 1024 + t * 4;
#pragma unroll
      for (int rc = 0; rc < 16; rc++){
        const float4 v = *(const float4*)(cp + rc * 1024);
        s.x += v.x; s.y += v.y; s.z += v.z; s.w += v.w;
      }
      *(float4*)&bvec[t * 4] = make_float4(MUV * frcp(s.x), MUV * frcp(s.y),
                                           MUV * frcp(s.z), MUV * frcp(s.w));
    }
    __syncthreads();

    // row pass: r_i = sum_j Kx[i][j] * b_j ; a_i = mu / r_i
#pragma unroll 2
    for (int rr = 0; rr < 16; rr++){
      const int i = w * 16 + rr;
      const int sw = (i & 7) << 4;
      float sum = 0.f;
#pragma unroll
      for (int c = 0; c < 4; c++){
        const ushort4 k4 = *(const ushort4*)((char*)Kx + i * 2048 + ((c * 512 + lane * 8) ^ sw));
        const float4  b4 = *(const float4*)&bvec[c * 256 + lane * 4];
        sum += bf2f(k4.x) * b4.x + bf2f(k4.y) * b4.y + bf2f(k4.z) * b4.z + bf2f(k4.w) * b4.w;
      }
#pragma unroll
      for (int off = 32; off; off >>= 1) sum += __shfl_xor(sum, off);
      if (lane == 0) avec[i] = MUV * frcp(sum);
    }
    __syncthreads();

    // col pass: cpart[bid][j] = sum_{i in chunk} Kx[i][j] * a_i  (plain writes, own slice)
    {
      float4 ca = make_float4(0, 0, 0, 0);
      const int bo = t * 8;
#pragma unroll 8
      for (int i = 0; i < 64; i++){
        const ushort4 k4 = *(const ushort4*)((char*)Kx + i * 2048 + (bo ^ ((i & 7) << 4)));
        const float a = avec[i];
        ca.x += bf2f(k4.x) * a; ca.y += bf2f(k4.y) * a;
        ca.z += bf2f(k4.z) * a; ca.w += bf2f(k4.w) * a;
      }
      *(float4*)(cpart + (size_t)bid * 1024 + t * 4) = ca;
    }
    __threadfence();
    grid.sync();
  }

  // final b_10 = nu / c_10
  {
    float4 s = make_float4(0, 0, 0, 0);
    const float* cp = cpart + (size_t)h * 16 * 1024 + t * 4;
#pragma unroll
    for (int rc = 0; rc < 16; rc++){
      const float4 v = *(const float4*)(cp + rc * 1024);
      s.x += v.x; s.y += v.y; s.z += v.z; s.w += v.w;
    }
    *(float4*)&bvec[t * 4] = make_float4(MUV * frcp(s.x), MUV * frcp(s.y),
                                         MUV * frcp(s.z), MUV * frcp(s.w));
  }
  __threadfence();
  grid.sync();   // everyone done reading cpart before p_attn overwrites it
  __syncthreads();

  // ---------------- Phase 3: p = 1024*a*K*b (fp32, coalesced) + out = P V (MFMA) ----------------
#pragma unroll 2
  for (int rr = 0; rr < 16; rr++){
    const int i = w * 16 + rr;
    const int sw = (i & 7) << 4;
    const float ai = 1024.f * avec[i];
    float* prow = Pmat + ((size_t)(h * SEQ + r0 + i)) * SEQ;
#pragma unroll
    for (int c = 0; c < 4; c++){
      const ushort4 k4 = *(const ushort4*)((char*)Kx + i * 2048 + ((c * 512 + lane * 8) ^ sw));
      const float4  b4 = *(const float4*)&bvec[c * 256 + lane * 4];
      float4 p4 = make_float4(ai * b4.x * bf2f(k4.x), ai * b4.y * bf2f(k4.y),
                              ai * b4.z * bf2f(k4.z), ai * b4.w * bf2f(k4.w));
      *(float4*)(prow + c * 256 + lane * 4) = p4;
    }
  }

  // PV: out[r][d] = sum_j P[r][j] V[j][d], A = P (bf16 from Kx), B = V (bf16 staged)
  const int prowi = w * 16 + fr;
  const float ai_frag = 1024.f * avec[prowi];
  f32x4 oacc[4] = {};

  for (int vc = 0; vc < 16; vc++){
    __syncthreads();
    {
      const int r = t >> 4, c4 = (t & 15) * 4;
      const float* g = Vg + (size_t)vc * 64 * DIM;
#pragma unroll
      for (int q = 0; q < 4; q++){
        const int row = r + 16 * q;
        const float4 v = *(const float4*)(g + row * DIM + c4);
        ushort4 u4 = make_ushort4(f2bf(v.x), f2bf(v.y), f2bf(v.z), f2bf(v.w));
        *(ushort4*)((char*)ST + row * 128 + ((c4 * 2) ^ ((row & 7) << 4))) = u4;
      }
    }
    __syncthreads();
#pragma unroll
    for (int half = 0; half < 2; half++){
      const int k0 = vc * 64 + half * 32 + fq * 8;     // global j of this lane's A k-slice
      const bf16x8 kx8 = *(const bf16x8*)((char*)Kx + prowi * 2048 + ((k0 * 2) ^ ((prowi & 7) << 4)));
      const float4 b0 = *(const float4*)&bvec[k0];
      const float4 b1 = *(const float4*)&bvec[k0 + 4];
      const float bv[8] = {b0.x, b0.y, b0.z, b0.w, b1.x, b1.y, b1.z, b1.w};
      union { unsigned short u[8]; bf16x8 v; } pa;
#pragma unroll
      for (int e = 0; e < 8; e++)
        pa.u[e] = f2bf(ai_frag * bv[e] * bf2f((unsigned short)kx8[e]));
#pragma unroll
      for (int ct = 0; ct < 4; ct++){
        // B[k][col] = V[j = half*32+fq*8+e][d = ct*16+fr], 8 u16 LDS reads -> 4 dwords
        union { unsigned int wv[4]; bf16x8 v; } vb;
        const int dcol = (ct * 16 + fr) * 2;
#pragma unroll
        for (int e2 = 0; e2 < 4; e2++){
          const int j0 = half * 32 + fq * 8 + e2 * 2;
          const unsigned short lo = *(const unsigned short*)((char*)ST + j0 * 128 + (dcol ^ ((j0 & 7) << 4)));
          const unsigned short hi = *(const unsigned short*)((char*)ST + (j0 + 1) * 128 + (dcol ^ (((j0 + 1) & 7) << 4)));
          vb.wv[e2] = (unsigned int)lo | ((unsigned int)hi << 16);
        }
        oacc[ct] = __builtin_amdgcn_mfma_f32_16x16x32_bf16(pa.v, vb.v, oacc[ct], 0, 0, 0);
      }
    }
  }

  float* og = out + ((size_t)h * SEQ + r0 + w * 16) * DIM;
#pragma unroll
  for (int ct = 0; ct < 4; ct++)
#pragma unroll
    for (int r = 0; r < 4; r++)
      og[(fq * 4 + r) * DIM + ct * 16 + fr] = oacc[ct][r];
}

extern "C" void kernel_launch(void* const* d_in, const int* in_sizes, int n_in,
                              void* d_out, int out_size, void* d_ws, size_t ws_size,
                              hipStream_t stream) {
  const float* Q   = (const float*)d_in[0];
  const float* Kin = (const float*)d_in[1];
  const float* V   = (const float*)d_in[2];
  float* out = (float*)d_out;
  void* args[] = {(void*)&Q, (void*)&Kin, (void*)&V, (void*)&out};
  hipLaunchCooperativeKernel((const void*)sinkhorn_fused, dim3(256), dim3(256),
                             args, 0, stream);
}

// Round 4
// 274.859 us; speedup vs baseline: 3.1593x; 3.1593x over previous
//
#include <hip/hip_runtime.h>
#include <math.h>

#define NH   16
#define SEQ  1024
#define DIM  64
#define MUV  (1.0f/1024.0f)
#define KSTRIDE 2048   // ushorts per Kexp row slot (4KB slot, first 2KB = 1024 bf16 used)

typedef __attribute__((ext_vector_type(8))) short bf16x8;
typedef __attribute__((ext_vector_type(4))) float f32x4;

__device__ __forceinline__ float frcp(float x){ return __builtin_amdgcn_rcpf(x); }
__device__ __forceinline__ float bf2f(unsigned short u){
  union { unsigned int i; float f; } v; v.i = ((unsigned int)u) << 16; return v.f;
}
__device__ __forceinline__ unsigned short f2bf(float f){
  union { float f; unsigned int i; } v; v.f = f;
  return (unsigned short)((v.i + 0x7FFFu + ((v.i >> 16) & 1u)) >> 16);
}

// ---------------- Kernel 1: Kexp = exp(-exp(Q K^T)/8), bf16, strided slots -------------
// grid (16 row-chunks, 16 heads), 256 thr. 64 Q-rows per block, all 1024 K cols.
__global__ __launch_bounds__(256) void qk_kernel(const float* __restrict__ Q,
                                                 const float* __restrict__ Kin,
                                                 unsigned short* __restrict__ Kb) {
  __shared__ unsigned short QS[64 * 64];   // bf16, row stride 128B, XOR-swizzled
  __shared__ unsigned short ST[64 * 64];   // K chunk stage
  __shared__ unsigned short Ob[64 * 64];   // output bounce tile (linear)
  const int h  = blockIdx.y;
  const int r0 = blockIdx.x * 64;
  const int t  = threadIdx.x;
  const int lane = t & 63, w = t >> 6, fr = lane & 15, fq = lane >> 4;
  const float* Qg = Q   + ((size_t)h * SEQ + r0) * DIM;
  const float* Kg = Kin + (size_t)h * SEQ * DIM;

  { // stage Q (64x64 f32 -> bf16, swizzled)
    const int r = t >> 4, c4 = (t & 15) * 4;
#pragma unroll
    for (int q = 0; q < 4; q++){
      const int row = r + 16 * q;
      const float4 v = *(const float4*)(Qg + row * DIM + c4);
      ushort4 u4 = make_ushort4(f2bf(v.x), f2bf(v.y), f2bf(v.z), f2bf(v.w));
      *(ushort4*)((char*)QS + row * 128 + ((c4 * 2) ^ ((row & 7) << 4))) = u4;
    }
  }
  __syncthreads();

  const int qrow = w * 16 + fr;
  const bf16x8 qa0 = *(const bf16x8*)((char*)QS + qrow * 128 + ((fq * 16)      ^ ((qrow & 7) << 4)));
  const bf16x8 qa1 = *(const bf16x8*)((char*)QS + qrow * 128 + ((64 + fq * 16) ^ ((qrow & 7) << 4)));

  for (int cc = 0; cc < 16; cc++){
    __syncthreads();   // protect ST and Ob reuse
    { // stage K chunk (64 rows)
      const int r = t >> 4, c4 = (t & 15) * 4;
      const float* g = Kg + (size_t)cc * 64 * DIM;
#pragma unroll
      for (int q = 0; q < 4; q++){
        const int row = r + 16 * q;
        const float4 v = *(const float4*)(g + row * DIM + c4);
        ushort4 u4 = make_ushort4(f2bf(v.x), f2bf(v.y), f2bf(v.z), f2bf(v.w));
        *(ushort4*)((char*)ST + row * 128 + ((c4 * 2) ^ ((row & 7) << 4))) = u4;
      }
    }
    __syncthreads();
#pragma unroll
    for (int ct = 0; ct < 4; ct++){
      const int krow = ct * 16 + fr;
      const bf16x8 kb0 = *(const bf16x8*)((char*)ST + krow * 128 + ((fq * 16)      ^ ((krow & 7) << 4)));
      const bf16x8 kb1 = *(const bf16x8*)((char*)ST + krow * 128 + ((64 + fq * 16) ^ ((krow & 7) << 4)));
      f32x4 acc = {0.f, 0.f, 0.f, 0.f};
      acc = __builtin_amdgcn_mfma_f32_16x16x32_bf16(qa0, kb0, acc, 0, 0, 0);
      acc = __builtin_amdgcn_mfma_f32_16x16x32_bf16(qa1, kb1, acc, 0, 0, 0);
#pragma unroll
      for (int r = 0; r < 4; r++){
        const int roww = w * 16 + fq * 4 + r;          // C layout: col=lane&15, row=(lane>>4)*4+r
        const float kv = __expf(-__expf(acc[r]) * 0.125f);
        Ob[roww * 64 + ct * 16 + fr] = f2bf(kv);
      }
    }
    __syncthreads();
    { // dump Ob -> global (coalesced 128B per row)
      const int row = t >> 2, c16 = (t & 3) * 16;
      unsigned short* dst = Kb + (size_t)(h * SEQ + r0 + row) * KSTRIDE + cc * 64 + c16;
      *(uint4*)dst       = *(const uint4*)&Ob[row * 64 + c16];
      *(uint4*)(dst + 8) = *(const uint4*)&Ob[row * 64 + c16 + 8];
    }
  }
}

// ---------------- Kernel 2: one full Sinkhorn iteration (row + col pass) ----------------
// grid (32 chunks, 16 heads) = 512 blocks, 2 blocks/CU. Chunk = 32 rows staged in LDS.
__global__ __launch_bounds__(256, 2) void sink_iter(const unsigned short* __restrict__ Kb,
                                                    const float* __restrict__ cprev,
                                                    float* __restrict__ cnext,
                                                    float* __restrict__ avg,
                                                    int first) {
  __shared__ unsigned short Ksh[32 * 1024];  // 64KB, linear, row stride 1024 u16
  __shared__ float bsh[1024];
  __shared__ float ash[32];
  const int h = blockIdx.y, ch = blockIdx.x, r0 = ch * 32, t = threadIdx.x;

  // b_j from previous column sums (32 slices)
  if (first){
    *(float4*)&bsh[t * 4] = make_float4(1.f, 1.f, 1.f, 1.f);
  } else {
    float4 s = make_float4(0, 0, 0, 0);
    const float* cp = cprev + (size_t)h * 32 * 1024 + t * 4;
#pragma unroll 8
    for (int sl = 0; sl < 32; sl++){
      const float4 v = *(const float4*)(cp + (size_t)sl * 1024);
      s.x += v.x; s.y += v.y; s.z += v.z; s.w += v.w;
    }
    *(float4*)&bsh[t * 4] = make_float4(MUV * frcp(s.x), MUV * frcp(s.y),
                                        MUV * frcp(s.z), MUV * frcp(s.w));
  }
  __syncthreads();

  // stage chunk + weighted row sums. 8 threads per row, 16B pieces.
  const int row = t >> 3, off8 = t & 7;
  const unsigned short* gk = Kb + (size_t)(h * SEQ + r0 + row) * KSTRIDE;
  float acc = 0.f;
#pragma unroll
  for (int p = 0; p < 16; p++){
    const int idx = (p * 8 + off8) * 8;                 // element index, 8 bf16 per piece
    const uint4 g = *(const uint4*)(gk + idx);
    *(uint4*)&Ksh[row * 1024 + idx] = g;
    const float4 b0 = *(const float4*)&bsh[idx];
    const float4 b1 = *(const float4*)&bsh[idx + 4];
    acc += bf2f((unsigned short)(g.x)) * b0.x + bf2f((unsigned short)(g.x >> 16)) * b0.y
         + bf2f((unsigned short)(g.y)) * b0.z + bf2f((unsigned short)(g.y >> 16)) * b0.w
         + bf2f((unsigned short)(g.z)) * b1.x + bf2f((unsigned short)(g.z >> 16)) * b1.y
         + bf2f((unsigned short)(g.w)) * b1.z + bf2f((unsigned short)(g.w >> 16)) * b1.w;
  }
#pragma unroll
  for (int m = 1; m < 8; m <<= 1) acc += __shfl_xor(acc, m);
  if (off8 == 0){
    const float a = MUV * frcp(acc);
    ash[row] = a;
    avg[h * SEQ + r0 + row] = a;     // last iteration's values win; used by pv/pwrite
  }
  __syncthreads();

  // col partials: thread owns 4 cols across the 32 staged rows
  float4 ca = make_float4(0, 0, 0, 0);
#pragma unroll 8
  for (int i = 0; i < 32; i++){
    const ushort4 k4 = *(const ushort4*)&Ksh[i * 1024 + t * 4];
    const float a = ash[i];
    ca.x += bf2f(k4.x) * a; ca.y += bf2f(k4.y) * a;
    ca.z += bf2f(k4.z) * a; ca.w += bf2f(k4.w) * a;
  }
  *(float4*)(cnext + ((size_t)h * 32 + ch) * 1024 + t * 4) = ca;
}

// ---------------- Kernel 3: out = P V via MFMA (runs BEFORE pwrite) ----------------
// grid (64 chunks, 16 heads) = 1024 blocks, 16 rows each, 2 blocks/CU.
__global__ __launch_bounds__(256, 2) void pv_kernel(const unsigned short* __restrict__ Kb,
                                                    const float* __restrict__ V,
                                                    const float* __restrict__ cpart,
                                                    const float* __restrict__ avg,
                                                    float* __restrict__ out) {
  __shared__ unsigned short Ksh[16 * 1024];  // 32KB, row stride 2048B, 16B-unit swizzled
  __shared__ unsigned short Vsh[256 * 64];   // 32KB, row stride 128B, swizzled
  __shared__ float bsh[1024];
  __shared__ float ash[16];
  const int h = blockIdx.y, ch = blockIdx.x, r0 = ch * 16, t = threadIdx.x;
  const int lane = t & 63, w = t >> 6, fr = lane & 15, fq = lane >> 4;

  { // b_j
    float4 s = make_float4(0, 0, 0, 0);
    const float* cp = cpart + (size_t)h * 32 * 1024 + t * 4;
#pragma unroll 8
    for (int sl = 0; sl < 32; sl++){
      const float4 v = *(const float4*)(cp + (size_t)sl * 1024);
      s.x += v.x; s.y += v.y; s.z += v.z; s.w += v.w;
    }
    *(float4*)&bsh[t * 4] = make_float4(MUV * frcp(s.x), MUV * frcp(s.y),
                                        MUV * frcp(s.z), MUV * frcp(s.w));
  }
  if (t < 16) ash[t] = 1024.f * avg[h * SEQ + r0 + t];

  { // stage K rows (16 x 2KB), swizzled in 16B units
#pragma unroll
    for (int s = 0; s < 8; s++){
      const int u = s * 256 + t;         // 2048 units total
      const int row = u >> 7, uo = u & 127;
      const unsigned short* src = Kb + (size_t)(h * SEQ + r0 + row) * KSTRIDE + uo * 8;
      *(uint4*)((char*)Ksh + row * 2048 + ((uo * 16) ^ ((row & 7) << 4))) = *(const uint4*)src;
    }
  }
  __syncthreads();

  const float ascale = ash[fr];
  f32x4 oacc = {0.f, 0.f, 0.f, 0.f};
  const float* Vg = V + (size_t)h * SEQ * DIM;

  for (int vq = 0; vq < 4; vq++){
    __syncthreads();   // protect Vsh from previous readers
    { // stage V rows [vq*256, +256) as bf16, swizzled
#pragma unroll
      for (int p = 0; p < 4; p++){
        const int j = p * 64 + (t >> 2);
        const int piece = t & 3;
        const float* g = Vg + (size_t)(vq * 256 + j) * DIM + piece * 16;
        union { unsigned short u[16]; uint4 q[2]; } pk;
#pragma unroll
        for (int k = 0; k < 4; k++){
          const float4 v = *(const float4*)(g + k * 4);
          pk.u[k*4+0] = f2bf(v.x); pk.u[k*4+1] = f2bf(v.y);
          pk.u[k*4+2] = f2bf(v.z); pk.u[k*4+3] = f2bf(v.w);
        }
        const int sw = (j & 7) << 4;
        *(uint4*)((char*)Vsh + j * 128 + (((piece * 32)      ) ^ sw)) = pk.q[0];
        *(uint4*)((char*)Vsh + j * 128 + (((piece * 32) + 16 ) ^ sw)) = pk.q[1];
      }
    }
    __syncthreads();
#pragma unroll
    for (int vc = 0; vc < 4; vc++){
#pragma unroll
      for (int half = 0; half < 2; half++){
        const int jl = vc * 64 + half * 32;           // local to Vsh
        const int jg = vq * 256 + jl;                 // global j
        const int k0 = jg + fq * 8;
        const bf16x8 kx8 = *(const bf16x8*)((char*)Ksh + fr * 2048 + ((k0 * 2) ^ ((fr & 7) << 4)));
        const float4 b0 = *(const float4*)&bsh[k0];
        const float4 b1 = *(const float4*)&bsh[k0 + 4];
        const float bv[8] = {b0.x, b0.y, b0.z, b0.w, b1.x, b1.y, b1.z, b1.w};
        union { unsigned short u[8]; bf16x8 v; } pa;
#pragma unroll
        for (int e = 0; e < 8; e++)
          pa.u[e] = f2bf(ascale * bv[e] * bf2f((unsigned short)kx8[e]));
        union { unsigned int wv[4]; bf16x8 v; } vb;
        const int dcol = (w * 16 + fr) * 2;
#pragma unroll
        for (int e2 = 0; e2 < 4; e2++){
          const int j0 = jl + fq * 8 + e2 * 2;
          const unsigned int lo = *(const unsigned short*)((char*)Vsh + j0 * 128 + (dcol ^ ((j0 & 7) << 4)));
          const unsigned int hi = *(const unsigned short*)((char*)Vsh + (j0 + 1) * 128 + (dcol ^ (((j0 + 1) & 7) << 4)));
          vb.wv[e2] = lo | (hi << 16);
        }
        oacc = __builtin_amdgcn_mfma_f32_16x16x32_bf16(pa.v, vb.v, oacc, 0, 0, 0);
      }
    }
  }

  float* og = out + ((size_t)h * SEQ + r0) * DIM + w * 16 + fr;
#pragma unroll
  for (int r = 0; r < 4; r++)
    og[(size_t)(fq * 4 + r) * DIM] = oacc[r];
}

// ---------------- Kernel 4: p_attn = (1024 a) * K * b, fp32, in-place over Kb slots ------
// grid (32 chunks, 16 heads) = 512 blocks, 2 blocks/CU. Stage->sync->overwrite = safe.
__global__ __launch_bounds__(256, 2) void pwrite_kernel(const unsigned short* __restrict__ Kb,
                                                        float* __restrict__ Pmat,
                                                        const float* __restrict__ cpart,
                                                        const float* __restrict__ avg) {
  __shared__ unsigned short Ksh[32 * 1024];
  __shared__ float bsh[1024];
  __shared__ float ash[32];
  const int h = blockIdx.y, ch = blockIdx.x, r0 = ch * 32, t = threadIdx.x;

  { // b_j
    float4 s = make_float4(0, 0, 0, 0);
    const float* cp = cpart + (size_t)h * 32 * 1024 + t * 4;
#pragma unroll 8
    for (int sl = 0; sl < 32; sl++){
      const float4 v = *(const float4*)(cp + (size_t)sl * 1024);
      s.x += v.x; s.y += v.y; s.z += v.z; s.w += v.w;
    }
    *(float4*)&bsh[t * 4] = make_float4(MUV * frcp(s.x), MUV * frcp(s.y),
                                        MUV * frcp(s.z), MUV * frcp(s.w));
  }
  if (t < 32) ash[t] = 1024.f * avg[h * SEQ + r0 + t];

  const int row = t >> 3, off8 = t & 7;
  const unsigned short* gk = Kb + (size_t)(h * SEQ + r0 + row) * KSTRIDE;
#pragma unroll
  for (int p = 0; p < 16; p++){
    const int idx = (p * 8 + off8) * 8;
    *(uint4*)&Ksh[row * 1024 + idx] = *(const uint4*)(gk + idx);
  }
  __syncthreads();   // all reads of this block's slots complete before overwrite

  const float ar = ash[row];
  float* prow = Pmat + (size_t)(h * SEQ + r0 + row) * SEQ;
#pragma unroll
  for (int p = 0; p < 16; p++){
    const int idx = (p * 8 + off8) * 8;
    const uint4 g = *(const uint4*)&Ksh[row * 1024 + idx];
    const float4 b0 = *(const float4*)&bsh[idx];
    const float4 b1 = *(const float4*)&bsh[idx + 4];
    float4 o0, o1;
    o0.x = ar * b0.x * bf2f((unsigned short)(g.x));
    o0.y = ar * b0.y * bf2f((unsigned short)(g.x >> 16));
    o0.z = ar * b0.z * bf2f((unsigned short)(g.y));
    o0.w = ar * b0.w * bf2f((unsigned short)(g.y >> 16));
    o1.x = ar * b1.x * bf2f((unsigned short)(g.z));
    o1.y = ar * b1.y * bf2f((unsigned short)(g.z >> 16));
    o1.z = ar * b1.z * bf2f((unsigned short)(g.w));
    o1.w = ar * b1.w * bf2f((unsigned short)(g.w >> 16));
    *(float4*)(prow + idx)     = o0;
    *(float4*)(prow + idx + 4) = o1;
  }
}

extern "C" void kernel_launch(void* const* d_in, const int* in_sizes, int n_in,
                              void* d_out, int out_size, void* d_ws, size_t ws_size,
                              hipStream_t stream) {
  (void)in_sizes; (void)n_in; (void)out_size; (void)ws_size;
  const float* Q   = (const float*)d_in[0];
  const float* Kin = (const float*)d_in[1];
  const float* V   = (const float*)d_in[2];
  float* out  = (float*)d_out;
  float* Pmat = out + (size_t)NH * SEQ * DIM;          // p_attn region (64MB)
  unsigned short* Kb = (unsigned short*)Pmat;          // bf16 Kexp in 4KB row slots

  float* ws  = (float*)d_ws;
  float* cp0 = ws;                                     // 16*32*1024 f32 (2MB)
  float* cp1 = ws + (size_t)NH * 32 * SEQ;             // 2MB
  float* avg = ws + (size_t)2 * NH * 32 * SEQ;         // 16*1024 f32 (64KB)

  qk_kernel<<<dim3(16, 16), 256, 0, stream>>>(Q, Kin, Kb);
  for (int it = 0; it < 10; it++){
    const float* cprev = (it & 1) ? cp0 : cp1;
    float*       cnext = (it & 1) ? cp1 : cp0;
    sink_iter<<<dim3(32, 16), 256, 0, stream>>>(Kb, cprev, cnext, avg, it == 0 ? 1 : 0);
  }
  // NOTE: pv must run before pwrite (pwrite destroys Kexp in-place).
  pv_kernel<<<dim3(64, 16), 256, 0, stream>>>(Kb, V, cp1, avg, out);
  pwrite_kernel<<<dim3(32, 16), 256, 0, stream>>>(Kb, Pmat, cp1, avg);
}

// Round 5
// 271.478 us; speedup vs baseline: 3.1986x; 1.0125x over previous
//
#include <hip/hip_runtime.h>
#include <math.h>

#define NH   16
#define SEQ  1024
#define DIM  64
#define MUV  (1.0f/1024.0f)

typedef __attribute__((ext_vector_type(8))) short bf16x8;
typedef __attribute__((ext_vector_type(4))) float f32x4;

__device__ __forceinline__ float frcp(float x){ return __builtin_amdgcn_rcpf(x); }
__device__ __forceinline__ float bf2f(unsigned short u){
  union { unsigned int i; float f; } v; v.i = ((unsigned int)u) << 16; return v.f;
}
__device__ __forceinline__ unsigned short f2bf(float f){
  union { float f; unsigned int i; } v; v.f = f;
  return (unsigned short)((v.i + 0x7FFFu + ((v.i >> 16) & 1u)) >> 16);
}

// ---------------- prep: Q,K -> bf16 linear; V -> bf16 transposed Vt[h][d][j] ----------------
__global__ __launch_bounds__(256) void prep_kernel(const float* __restrict__ Q,
                                                   const float* __restrict__ K,
                                                   const float* __restrict__ V,
                                                   unsigned short* __restrict__ Qbf,
                                                   unsigned short* __restrict__ Kbf,
                                                   unsigned short* __restrict__ Vt) {
  __shared__ float Vsh[64][68];
  const int h = blockIdx.y, ck = blockIdx.x, t = threadIdx.x;
  const int r = t >> 2, cp = (t & 3) * 16;
  const size_t gbase = ((size_t)h * SEQ + ck * 64 + r) * DIM + cp;
  {
    union { unsigned short u[16]; uint4 q[2]; } pk;
#pragma unroll
    for (int k = 0; k < 4; k++){
      const float4 v = *(const float4*)(Q + gbase + k * 4);
      pk.u[k*4+0]=f2bf(v.x); pk.u[k*4+1]=f2bf(v.y); pk.u[k*4+2]=f2bf(v.z); pk.u[k*4+3]=f2bf(v.w);
    }
    *(uint4*)(Qbf + gbase) = pk.q[0];
    *(uint4*)(Qbf + gbase + 8) = pk.q[1];
  }
  {
    union { unsigned short u[16]; uint4 q[2]; } pk;
#pragma unroll
    for (int k = 0; k < 4; k++){
      const float4 v = *(const float4*)(K + gbase + k * 4);
      pk.u[k*4+0]=f2bf(v.x); pk.u[k*4+1]=f2bf(v.y); pk.u[k*4+2]=f2bf(v.z); pk.u[k*4+3]=f2bf(v.w);
    }
    *(uint4*)(Kbf + gbase) = pk.q[0];
    *(uint4*)(Kbf + gbase + 8) = pk.q[1];
  }
  {
#pragma unroll
    for (int k = 0; k < 4; k++)
      *(float4*)&Vsh[r][cp + k * 4] = *(const float4*)(V + gbase + k * 4);
    __syncthreads();
    const int dd = t >> 2, jp = (t & 3) * 16;
    union { unsigned short u[16]; uint4 q[2]; } pk;
#pragma unroll
    for (int k = 0; k < 16; k++) pk.u[k] = f2bf(Vsh[jp + k][dd]);
    unsigned short* dst = Vt + ((size_t)h * DIM + dd) * SEQ + ck * 64 + jp;
    *(uint4*)dst       = pk.q[0];
    *(uint4*)(dst + 8) = pk.q[1];
  }
}

// ---------------- one Sinkhorn iteration: recompute Kexp chunk in LDS, row+col pass ----------------
// grid (32 chunks, 16 heads) = 512 blocks, 2 blocks/CU.
__global__ __launch_bounds__(256, 2)
void sink_rc(const unsigned short* __restrict__ Qbf,
             const unsigned short* __restrict__ Kbf,
             const float* __restrict__ cprev,
             float* __restrict__ cnext,
             float* __restrict__ avg,
             int first)
{
  __shared__ unsigned short Ksh[32 * 1024];   // 64KB bf16 kexp, row stride 2048B, XOR-swizzled
  __shared__ float bsh[1024];
  __shared__ float rsum[4][32];
  __shared__ float ash[32];
  const int h = blockIdx.y, ch = blockIdx.x, r0 = ch * 32, t = threadIdx.x;
  const int lane = t & 63, w = t >> 6, fr = lane & 15, fq = lane >> 4;

  if (first){
    *(float4*)&bsh[t * 4] = make_float4(1.f, 1.f, 1.f, 1.f);
  } else {
    float4 s = make_float4(0, 0, 0, 0);
    const float* cp = cprev + (size_t)h * 32 * 1024 + t * 4;
#pragma unroll 8
    for (int sl = 0; sl < 32; sl++){
      const float4 v = *(const float4*)(cp + (size_t)sl * 1024);
      s.x += v.x; s.y += v.y; s.z += v.z; s.w += v.w;
    }
    *(float4*)&bsh[t * 4] = make_float4(MUV * frcp(s.x), MUV * frcp(s.y),
                                        MUV * frcp(s.z), MUV * frcp(s.w));
  }
  __syncthreads();

  // A-frags: Q rows r0+{0..15} (tile0), r0+{16..31} (tile1), k split 0/32
  const unsigned short* qp = Qbf + ((size_t)h * SEQ + r0 + fr) * DIM + fq * 8;
  const bf16x8 qa00 = *(const bf16x8*)qp;
  const bf16x8 qa01 = *(const bf16x8*)(qp + 32);
  const bf16x8 qa10 = *(const bf16x8*)(qp + 16 * DIM);
  const bf16x8 qa11 = *(const bf16x8*)(qp + 16 * DIM + 32);

  float rp[8] = {0.f,0.f,0.f,0.f,0.f,0.f,0.f,0.f};

#pragma unroll 2
  for (int cc = 0; cc < 16; cc++){
    const int c0 = cc * 64 + w * 16;
    const unsigned short* kp = Kbf + ((size_t)h * SEQ + c0 + fr) * DIM + fq * 8;
    const bf16x8 kb0 = *(const bf16x8*)kp;
    const bf16x8 kb1 = *(const bf16x8*)(kp + 32);
    f32x4 a0 = {0.f,0.f,0.f,0.f}, a1 = {0.f,0.f,0.f,0.f};
    a0 = __builtin_amdgcn_mfma_f32_16x16x32_bf16(qa00, kb0, a0, 0, 0, 0);
    a0 = __builtin_amdgcn_mfma_f32_16x16x32_bf16(qa01, kb1, a0, 0, 0, 0);
    a1 = __builtin_amdgcn_mfma_f32_16x16x32_bf16(qa10, kb0, a1, 0, 0, 0);
    a1 = __builtin_amdgcn_mfma_f32_16x16x32_bf16(qa11, kb1, a1, 0, 0, 0);
    const float bcol = bsh[c0 + fr];
    const int col2 = (c0 + fr) * 2;
#pragma unroll
    for (int r = 0; r < 4; r++){
      const int row0 = fq * 4 + r;
      const float kv0 = __expf(-0.125f * __expf(a0[r]));
      const unsigned short ku0 = f2bf(kv0);
      *(unsigned short*)((char*)Ksh + row0 * 2048 + (col2 ^ ((row0 & 7) << 4))) = ku0;
      rp[r] += bf2f(ku0) * bcol;
      const int row1 = 16 + fq * 4 + r;
      const float kv1 = __expf(-0.125f * __expf(a1[r]));
      const unsigned short ku1 = f2bf(kv1);
      *(unsigned short*)((char*)Ksh + row1 * 2048 + (col2 ^ ((row1 & 7) << 4))) = ku1;
      rp[4 + r] += bf2f(ku1) * bcol;
    }
  }

  // reduce row partials across fr lanes (bits 0..3)
#pragma unroll
  for (int m = 1; m <= 8; m <<= 1){
#pragma unroll
    for (int i = 0; i < 8; i++) rp[i] += __shfl_xor(rp[i], m);
  }
  if (fr == 0){
#pragma unroll
    for (int r = 0; r < 4; r++){
      rsum[w][fq * 4 + r]      = rp[r];
      rsum[w][16 + fq * 4 + r] = rp[4 + r];
    }
  }
  __syncthreads();
  if (t < 32){
    const float rs = rsum[0][t] + rsum[1][t] + rsum[2][t] + rsum[3][t];
    const float a = MUV * frcp(rs);
    ash[t] = a;
    avg[h * SEQ + r0 + t] = a;      // last iteration's a wins
  }
  __syncthreads();

  // col partials: thread owns cols 4t..4t+3 across the 32 rows
  float4 ca = make_float4(0, 0, 0, 0);
  const int bo = t * 8;
#pragma unroll 8
  for (int i = 0; i < 32; i++){
    const ushort4 k4 = *(const ushort4*)((char*)Ksh + i * 2048 + (bo ^ ((i & 7) << 4)));
    const float a = ash[i];
    ca.x += bf2f(k4.x) * a; ca.y += bf2f(k4.y) * a;
    ca.z += bf2f(k4.z) * a; ca.w += bf2f(k4.w) * a;
  }
  *(float4*)(cnext + ((size_t)h * 32 + ch) * 1024 + t * 4) = ca;
}

// ---------------- final: recompute Kexp, write p (fp32) and out = P V ----------------
// grid (32 chunks, 16 heads) = 512 blocks, 2 blocks/CU.
__global__ __launch_bounds__(256, 2)
void final_rc(const unsigned short* __restrict__ Qbf,
              const unsigned short* __restrict__ Kbf,
              const unsigned short* __restrict__ Vt,
              const float* __restrict__ cpart,
              const float* __restrict__ avg,
              float* __restrict__ Pmat,
              float* __restrict__ out)
{
  __shared__ unsigned short Ksh[32 * 1024];
  __shared__ float bsh[1024];
  __shared__ float ash[32];
  const int h = blockIdx.y, ch = blockIdx.x, r0 = ch * 32, t = threadIdx.x;
  const int lane = t & 63, w = t >> 6, fr = lane & 15, fq = lane >> 4;

  { // final b = nu / c
    float4 s = make_float4(0, 0, 0, 0);
    const float* cp = cpart + (size_t)h * 32 * 1024 + t * 4;
#pragma unroll 8
    for (int sl = 0; sl < 32; sl++){
      const float4 v = *(const float4*)(cp + (size_t)sl * 1024);
      s.x += v.x; s.y += v.y; s.z += v.z; s.w += v.w;
    }
    *(float4*)&bsh[t * 4] = make_float4(MUV * frcp(s.x), MUV * frcp(s.y),
                                        MUV * frcp(s.z), MUV * frcp(s.w));
  }
  if (t < 32) ash[t] = 1024.f * avg[h * SEQ + r0 + t];

  const unsigned short* qp = Qbf + ((size_t)h * SEQ + r0 + fr) * DIM + fq * 8;
  const bf16x8 qa00 = *(const bf16x8*)qp;
  const bf16x8 qa01 = *(const bf16x8*)(qp + 32);
  const bf16x8 qa10 = *(const bf16x8*)(qp + 16 * DIM);
  const bf16x8 qa11 = *(const bf16x8*)(qp + 16 * DIM + 32);

#pragma unroll 2
  for (int cc = 0; cc < 16; cc++){
    const int c0 = cc * 64 + w * 16;
    const unsigned short* kp = Kbf + ((size_t)h * SEQ + c0 + fr) * DIM + fq * 8;
    const bf16x8 kb0 = *(const bf16x8*)kp;
    const bf16x8 kb1 = *(const bf16x8*)(kp + 32);
    f32x4 a0 = {0.f,0.f,0.f,0.f}, a1 = {0.f,0.f,0.f,0.f};
    a0 = __builtin_amdgcn_mfma_f32_16x16x32_bf16(qa00, kb0, a0, 0, 0, 0);
    a0 = __builtin_amdgcn_mfma_f32_16x16x32_bf16(qa01, kb1, a0, 0, 0, 0);
    a1 = __builtin_amdgcn_mfma_f32_16x16x32_bf16(qa10, kb0, a1, 0, 0, 0);
    a1 = __builtin_amdgcn_mfma_f32_16x16x32_bf16(qa11, kb1, a1, 0, 0, 0);
    const int col2 = (c0 + fr) * 2;
#pragma unroll
    for (int r = 0; r < 4; r++){
      const int row0 = fq * 4 + r;
      *(unsigned short*)((char*)Ksh + row0 * 2048 + (col2 ^ ((row0 & 7) << 4))) =
          f2bf(__expf(-0.125f * __expf(a0[r])));
      const int row1 = 16 + fq * 4 + r;
      *(unsigned short*)((char*)Ksh + row1 * 2048 + (col2 ^ ((row1 & 7) << 4))) =
          f2bf(__expf(-0.125f * __expf(a1[r])));
    }
  }
  __syncthreads();

  // p-dump: p = (1024 a_i) * kexp * b_j, fp32, coalesced 256B segments
  {
    const int prow = t >> 3, pc = t & 7;
    const float ar = ash[prow];
    const int swp = (prow & 7) << 4;
    float* pg = Pmat + ((size_t)h * SEQ + r0 + prow) * SEQ;
#pragma unroll
    for (int p16 = 0; p16 < 16; p16++){
      const int colb = (p16 * 8 + pc) * 8;
      const uint4 kq = *(const uint4*)((char*)Ksh + prow * 2048 + ((colb * 2) ^ swp));
      const float4 b0 = *(const float4*)&bsh[colb];
      const float4 b1 = *(const float4*)&bsh[colb + 4];
      float4 o0, o1;
      o0.x = ar * b0.x * bf2f((unsigned short)(kq.x));
      o0.y = ar * b0.y * bf2f((unsigned short)(kq.x >> 16));
      o0.z = ar * b0.z * bf2f((unsigned short)(kq.y));
      o0.w = ar * b0.w * bf2f((unsigned short)(kq.y >> 16));
      o1.x = ar * b1.x * bf2f((unsigned short)(kq.z));
      o1.y = ar * b1.y * bf2f((unsigned short)(kq.z >> 16));
      o1.z = ar * b1.z * bf2f((unsigned short)(kq.w));
      o1.w = ar * b1.w * bf2f((unsigned short)(kq.w >> 16));
      *(float4*)(pg + colb)     = o0;
      *(float4*)(pg + colb + 4) = o1;
    }
  }

  // PV: A = p (bf16, built on the fly), B = Vt direct 16B loads
  f32x4 o0 = {0.f,0.f,0.f,0.f}, o1 = {0.f,0.f,0.f,0.f};
  const float ar0 = ash[fr];
  const float ar1 = ash[16 + fr];
  const int sw0 = (fr & 7) << 4;   // (16+fr)&7 == fr&7
  const char* kr0 = (const char*)Ksh + fr * 2048;
  const char* kr1 = (const char*)Ksh + (16 + fr) * 2048;
  const unsigned short* vp = Vt + ((size_t)h * DIM + w * 16 + fr) * SEQ;
#pragma unroll 2
  for (int jc = 0; jc < 32; jc++){
    const int jb = jc * 32 + fq * 8;
    const bf16x8 vb = *(const bf16x8*)(vp + jb);
    const float4 b0 = *(const float4*)&bsh[jb];
    const float4 b1 = *(const float4*)&bsh[jb + 4];
    const float bv[8] = {b0.x, b0.y, b0.z, b0.w, b1.x, b1.y, b1.z, b1.w};
    const bf16x8 k0 = *(const bf16x8*)(kr0 + ((jb * 2) ^ sw0));
    const bf16x8 k1 = *(const bf16x8*)(kr1 + ((jb * 2) ^ sw0));
    union { unsigned short u[8]; bf16x8 v; } pa0, pa1;
#pragma unroll
    for (int e = 0; e < 8; e++){
      pa0.u[e] = f2bf(ar0 * bv[e] * bf2f((unsigned short)k0[e]));
      pa1.u[e] = f2bf(ar1 * bv[e] * bf2f((unsigned short)k1[e]));
    }
    o0 = __builtin_amdgcn_mfma_f32_16x16x32_bf16(pa0.v, vb, o0, 0, 0, 0);
    o1 = __builtin_amdgcn_mfma_f32_16x16x32_bf16(pa1.v, vb, o1, 0, 0, 0);
  }

  float* og = out + ((size_t)h * SEQ + r0) * DIM + w * 16 + fr;
#pragma unroll
  for (int r = 0; r < 4; r++)
    og[(size_t)(fq * 4 + r) * DIM] = o0[r];
  float* og1 = og + (size_t)16 * DIM;
#pragma unroll
  for (int r = 0; r < 4; r++)
    og1[(size_t)(fq * 4 + r) * DIM] = o1[r];
}

extern "C" void kernel_launch(void* const* d_in, const int* in_sizes, int n_in,
                              void* d_out, int out_size, void* d_ws, size_t ws_size,
                              hipStream_t stream) {
  (void)in_sizes; (void)n_in; (void)out_size; (void)ws_size;
  const float* Q = (const float*)d_in[0];
  const float* K = (const float*)d_in[1];
  const float* V = (const float*)d_in[2];
  float* out  = (float*)d_out;
  float* Pmat = out + (size_t)NH * SEQ * DIM;

  unsigned short* Qbf = (unsigned short*)d_ws;                 // 2 MB
  unsigned short* Kbf = Qbf + (size_t)NH * SEQ * DIM;          // 2 MB
  unsigned short* Vt  = Kbf + (size_t)NH * SEQ * DIM;          // 2 MB
  float* cp0 = (float*)(Vt + (size_t)NH * SEQ * DIM);          // 2 MB
  float* cp1 = cp0 + (size_t)NH * 32 * SEQ;                    // 2 MB
  float* avg = cp1 + (size_t)NH * 32 * SEQ;                    // 64 KB

  prep_kernel<<<dim3(16, 16), 256, 0, stream>>>(Q, K, V, Qbf, Kbf, Vt);
  for (int it = 0; it < 10; it++){
    const float* cprev = (it & 1) ? cp0 : cp1;
    float*       cnext = (it & 1) ? cp1 : cp0;
    sink_rc<<<dim3(32, 16), 256, 0, stream>>>(Qbf, Kbf, cprev, cnext, avg, it == 0 ? 1 : 0);
  }
  final_rc<<<dim3(32, 16), 256, 0, stream>>>(Qbf, Kbf, Vt, cp1, avg, Pmat, out);
}